// Round 27
// baseline (363.895 us; speedup 1.0000x reference)
//
#include <hip/hip_runtime.h>
#include <math.h>

#define N_NODES 100000
#define N_EDGES 3200000
#define D_FEAT 256
#define GC_HID 20
#define DEC_HID 40
#define Z_DIM 32

#define EPB 2048          // edges per block
#define NBLK 1563         // ceil(3.2M / 2048)
#define SB 392            // node buckets of 256 (392*256 = 100352)
#define SBSH 8
#define S2CAP 12288       // per-bucket record cap

// ---------------- ws layout (bytes) ----------------
// h_pre (bf16 [N][20]) @ 0          4,000,000
// agg   (bf16 [N][20]) @ 8,000,000  4,000,000
// grec   @16,000,000  12,804,096
// pml (bf16 [N][64]) @28,804,096  12,800,000
// cnt_r (u16 [NBLK][SB]) @41,608,192  1,225,392
// pref_t @42,836,720   2,450,784
// row_ptr@45,287,504     400,004
// gtot   @45,687,508       1,568
// gbase  @45,689,076       1,572
// rs_s   @45,690,648     400,000
// rec_s  @46,090,648   3,201,024
// srow_s @49,291,672   1,228,518
// Wpack  @50,520,192      98,304   end = 50,618,496

__device__ inline unsigned short f2bf(float f) {
    unsigned u = __float_as_uint(f);
    return (unsigned short)((u + 0x7FFFu + ((u >> 16) & 1u)) >> 16);
}
__device__ inline float bf2f(unsigned short h) {
    return __uint_as_float((unsigned)h << 16);
}
__device__ inline float bflo(unsigned w) { return __uint_as_float(w << 16); }
__device__ inline float bfhi(unsigned w) { return __uint_as_float(w & 0xFFFF0000u); }

// pack node-row weights: Wpack[k][0:20]=W1[k], [24:56]=Wmu[20+k], [56:88]=Wls[20+k]
__global__ __launch_bounds__(96) void k_wpack(const float* __restrict__ W1,
                                              const float* __restrict__ Wmu,
                                              const float* __restrict__ Wls,
                                              float* __restrict__ Wp) {
    int k = blockIdx.x, j = threadIdx.x;
    float v = 0.0f;
    if (j < 20) v = W1[k * GC_HID + j];
    else if (j >= 24 && j < 56) v = Wmu[(GC_HID + k) * Z_DIM + (j - 24)];
    else if (j >= 56 && j < 88) v = Wls[(GC_HID + k) * Z_DIM + (j - 56)];
    Wp[k * 96 + j] = v;
}

// receiver-bucket HISTOGRAM only (no local sort -- k_sort2 re-sorts within
// bucket anyway, so local order is worthless; R26 lesson) + sender u8
// counting sort for deg_s. ZERO global atomics.
__global__ __launch_bounds__(512) void k_hist(const int* __restrict__ snd,
                                              const int* __restrict__ rcv,
                                              unsigned char* __restrict__ rec_s,
                                              unsigned short* __restrict__ cnt_r,
                                              unsigned short* __restrict__ srow_s) {
    __shared__ int es[EPB];
    __shared__ unsigned hist[SB];
    __shared__ unsigned scan[SB + 1];
    __shared__ unsigned cur[SB];
    __shared__ unsigned char sorteds[EPB];
    int b = blockIdx.x, t = threadIdx.x;
    int base = b * EPB;
    int cnt = min(EPB, N_EDGES - base);
    for (int i = t; i < cnt; i += 512) es[i] = snd[base + i];
    for (int i = t; i < SB; i += 512) hist[i] = 0u;
    for (int i = t; i < SB + 1; i += 512) scan[i] = 0u;
    __syncthreads();
    for (int i = t; i < cnt; i += 512) {
        atomicAdd(&hist[rcv[base + i] >> SBSH], 1u);
        atomicAdd(&scan[(es[i] >> SBSH) + 1], 1u);
    }
    __syncthreads();
    for (int i = t; i < SB; i += 512)
        cnt_r[(size_t)b * SB + i] = (unsigned short)hist[i];
    // sender prefix scan + local counting sort -> rec_s (u8 local ids)
    for (int off = 1; off < SB + 1; off <<= 1) {
        unsigned v = (t >= off && t < SB + 1) ? scan[t - off] : 0u;
        __syncthreads();
        if (t < SB + 1) scan[t] += v;
        __syncthreads();
    }
    for (int i = t; i < SB + 1; i += 512) srow_s[(size_t)b * (SB + 1) + i] = (unsigned short)scan[i];
    if (t < SB) cur[t] = scan[t];
    __syncthreads();
    for (int i = t; i < cnt; i += 512) {
        int s = es[i];
        unsigned pos = atomicAdd(&cur[s >> SBSH], 1u);
        sorteds[pos] = (unsigned char)(s & 255);
    }
    __syncthreads();
    for (int i = t; i < cnt; i += 512) rec_s[(size_t)base + i] = sorteds[i];
}

// sender-degree via per-bucket LDS histogram over sender-sorted runs
__global__ __launch_bounds__(512) void k_degs(const unsigned char* __restrict__ rec_s,
                                              const unsigned short* __restrict__ srow_s,
                                              float* __restrict__ rs_s) {
    __shared__ unsigned h[256];
    int s = blockIdx.x, t = threadIdx.x;
    if (t < 256) h[t] = 0u;
    __syncthreads();
    for (int k = t; k < NBLK; k += 512) {
        const unsigned short* row = srow_s + (size_t)k * (SB + 1);
        unsigned st = row[s], en = row[s + 1];
        const unsigned char* rp = rec_s + (size_t)k * EPB;
        for (unsigned i = st; i < en; ++i) atomicAdd(&h[rp[i]], 1u);
    }
    __syncthreads();
    if (t < 256) {
        int n = (s << SBSH) + t;
        if (n < N_NODES) rs_s[n] = rsqrtf(fmaxf((float)h[t], 1.0f));
    }
}

// per-bucket prefix over block counts: pref_t[s][k], totals gtot[s]
__global__ __launch_bounds__(256) void k_scanB(const unsigned short* __restrict__ cnt_r,
                                               unsigned* __restrict__ pref_t,
                                               unsigned* __restrict__ gtot) {
    __shared__ unsigned buf[256];
    int s = blockIdx.x, t = threadIdx.x;
    unsigned run = 0;
    for (int k0 = 0; k0 < NBLK; k0 += 256) {
        int k = k0 + t;
        unsigned v = (k < NBLK) ? (unsigned)cnt_r[(size_t)k * SB + s] : 0u;
        buf[t] = v;
        __syncthreads();
        for (int off = 1; off < 256; off <<= 1) {
            unsigned x = (t >= off) ? buf[t - off] : 0u;
            __syncthreads();
            buf[t] += x;
            __syncthreads();
        }
        if (k < NBLK) pref_t[(size_t)s * NBLK + k] = run + (buf[t] - v);
        unsigned tot = buf[255];
        __syncthreads();
        run += tot;
    }
    if (t == 0) gtot[s] = run;
}

// exclusive scan of bucket totals -> gbase[SB+1]
__global__ __launch_bounds__(512) void k_scanG(const unsigned* __restrict__ gtot,
                                               unsigned* __restrict__ gbase) {
    __shared__ unsigned buf[SB];
    int t = threadIdx.x;
    if (t < SB) buf[t] = gtot[t];
    __syncthreads();
    for (int off = 1; off < SB; off <<= 1) {
        unsigned x = (t >= off && t < SB) ? buf[t - off] : 0u;
        __syncthreads();
        if (t < SB) buf[t] += x;
        __syncthreads();
    }
    if (t < SB) gbase[t + 1] = buf[t];
    if (t == 0) gbase[0] = 0u;
}

// direct scatter: re-read snd/rcv, write records straight to grec at
// gbase[s]+pref_t[s][b]+localpos (order within segment arbitrary --
// k_sort2 sorts it). Replaces rec_r write + gscat read (25.6 MB saved).
__global__ __launch_bounds__(256) void k_scat2(const int* __restrict__ snd,
                                               const int* __restrict__ rcv,
                                               const unsigned* __restrict__ pref_t,
                                               const unsigned* __restrict__ gbase,
                                               unsigned* __restrict__ grec) {
    __shared__ unsigned cur2[SB];
    int b = blockIdx.x, t = threadIdx.x;
    for (int s = t; s < SB; s += 256)
        cur2[s] = gbase[s] + pref_t[(size_t)s * NBLK + b];
    __syncthreads();
    int base = b * EPB;
    int cnt = min(EPB, N_EDGES - base);
    for (int i = t; i < cnt; i += 256) {
        int r = rcv[base + i];
        int s = snd[base + i];
        unsigned idx = atomicAdd(&cur2[r >> SBSH], 1u);
        grec[idx] = ((unsigned)(r & 255) << 17) | (unsigned)s;
    }
}

// within-bucket counting sort by local receiver (in-place) + CSR row_ptr
__global__ __launch_bounds__(256) void k_sort2(unsigned* __restrict__ grec,
                                               const unsigned* __restrict__ gbase,
                                               unsigned* __restrict__ row_ptr) {
    __shared__ unsigned recs[S2CAP];     // 48 KB
    __shared__ unsigned hist[256];
    __shared__ unsigned scan[256];
    __shared__ unsigned cur[256];
    int s = blockIdx.x, t = threadIdx.x;
    unsigned lo = gbase[s], hi = gbase[s + 1];
    unsigned cnt = min(hi - lo, (unsigned)S2CAP);
    for (unsigned i = t; i < cnt; i += 256) recs[i] = grec[lo + i];
    hist[t] = 0u;
    __syncthreads();
    for (unsigned i = t; i < cnt; i += 256) atomicAdd(&hist[recs[i] >> 17], 1u);
    __syncthreads();
    unsigned v = hist[t];
    scan[t] = v;
    __syncthreads();
    for (int off = 1; off < 256; off <<= 1) {
        unsigned x = (t >= off) ? scan[t - off] : 0u;
        __syncthreads();
        scan[t] += x;
        __syncthreads();
    }
    unsigned excl = scan[t] - v;
    {
        int n = (s << SBSH) + t;
        if (n <= N_NODES) row_ptr[n] = lo + excl;
    }
    cur[t] = excl;
    __syncthreads();
    for (unsigned i = t; i < cnt; i += 256) {
        unsigned rec = recs[i];
        unsigned pos = atomicAdd(&cur[rec >> 17], 1u);
        grec[lo + pos] = rec & 0x1FFFFu;
    }
}

// FUSED gather1 + gc2: block = 64 nodes x 5 lanes (320 thr).
// src is bf16 [N][20] (40B rows, fits XCD L2); lane q reads uint2 (4 bf16).
__global__ __launch_bounds__(320) void k_gg1(const unsigned* __restrict__ row_ptr,
                                             const unsigned* __restrict__ grec,
                                             const unsigned* __restrict__ src,
                                             const float* __restrict__ W2,
                                             const float* __restrict__ b2,
                                             const float* __restrict__ rs_s,
                                             unsigned short* __restrict__ h2_pre) {
    __shared__ float h1[64 * 21];          // 5,376 B
    __shared__ float Wsh[GC_HID * GC_HID];
    __shared__ float bsh[GC_HID];
    int t = threadIdx.x;
    if (t < GC_HID * GC_HID) Wsh[t] = W2[t];
    if (t >= 400 && t < 400 + GC_HID) bsh[t - 400] = b2[t - 400];
    int nl = t / 5, q = t % 5;
    int node = blockIdx.x * 64 + nl;
    bool live = (node < N_NODES);
    unsigned lo = 0, hi = 0;
    if (live) { lo = row_ptr[node]; hi = row_ptr[node + 1]; }
    float4 a0 = make_float4(0.f, 0.f, 0.f, 0.f);
    float4 a1 = make_float4(0.f, 0.f, 0.f, 0.f);
    float4 a2 = make_float4(0.f, 0.f, 0.f, 0.f);
    float4 a3 = make_float4(0.f, 0.f, 0.f, 0.f);
    const uint2* sp = (const uint2*)src;
    unsigned e = lo;
    for (; e + 4 <= hi; e += 4) {
        unsigned s0 = grec[e], s1 = grec[e + 1], s2 = grec[e + 2], s3 = grec[e + 3];
        uint2 u0 = sp[s0 * 5 + q];
        uint2 u1 = sp[s1 * 5 + q];
        uint2 u2 = sp[s2 * 5 + q];
        uint2 u3 = sp[s3 * 5 + q];
        a0.x += bflo(u0.x); a0.y += bfhi(u0.x); a0.z += bflo(u0.y); a0.w += bfhi(u0.y);
        a1.x += bflo(u1.x); a1.y += bfhi(u1.x); a1.z += bflo(u1.y); a1.w += bfhi(u1.y);
        a2.x += bflo(u2.x); a2.y += bfhi(u2.x); a2.z += bflo(u2.y); a2.w += bfhi(u2.y);
        a3.x += bflo(u3.x); a3.y += bfhi(u3.x); a3.z += bflo(u3.y); a3.w += bfhi(u3.y);
    }
    for (; e < hi; ++e) {
        unsigned s0 = grec[e];
        uint2 u0 = sp[s0 * 5 + q];
        a0.x += bflo(u0.x); a0.y += bfhi(u0.x); a0.z += bflo(u0.y); a0.w += bfhi(u0.y);
    }
    a0.x += a1.x + a2.x + a3.x;
    a0.y += a1.y + a2.y + a3.y;
    a0.z += a1.z + a2.z + a3.z;
    a0.w += a1.w + a2.w + a3.w;
    if (live) {
        float sc = rsqrtf(fmaxf((float)(hi - lo), 1.0f));
        float* row = &h1[nl * 21 + q * 4];
        row[0] = a0.x * sc; row[1] = a0.y * sc;
        row[2] = a0.z * sc; row[3] = a0.w * sc;
    }
    __syncthreads();
    if (t < 64) {
        int nn = blockIdx.x * 64 + t;
        if (nn < N_NODES) {
            float hv[GC_HID];
#pragma unroll
            for (int i = 0; i < GC_HID; ++i) hv[i] = h1[t * 21 + i];
            float o[GC_HID];
#pragma unroll
            for (int j = 0; j < GC_HID; ++j) o[j] = bsh[j];
#pragma unroll
            for (int i = 0; i < GC_HID; ++i) {
                float x = hv[i];
#pragma unroll
                for (int j = 0; j < GC_HID; ++j) o[j] = fmaf(x, Wsh[i * GC_HID + j], o[j]);
            }
            float mx = -1e30f;
#pragma unroll
            for (int j = 0; j < GC_HID; ++j) { o[j] = fmaxf(o[j], 0.0f); mx = fmaxf(mx, o[j]); }
            float s = 0.0f;
#pragma unroll
            for (int j = 0; j < GC_HID; ++j) { o[j] = __expf(o[j] - mx); s += o[j]; }
            float inv = rs_s[nn] / s;
            unsigned pk[10];
#pragma unroll
            for (int i = 0; i < 10; ++i) {
                float v0 = o[2*i] * inv, v1 = o[2*i+1] * inv;
                pk[i] = (unsigned)f2bf(v0) | ((unsigned)f2bf(v1) << 16);
            }
            uint2* op = (uint2*)(h2_pre + (size_t)nn * GC_HID);
#pragma unroll
            for (int i = 0; i < 5; ++i)
                op[i] = make_uint2(pk[2*i], pk[2*i+1]);
        }
    }
}

// FUSED gather2 + encoder finish: 512 thr, 64 nodes.
__global__ __launch_bounds__(512) void k_gg2(const unsigned* __restrict__ row_ptr,
                                             const unsigned* __restrict__ grec,
                                             const unsigned* __restrict__ src,
                                             const unsigned short* __restrict__ pml,
                                             const float* __restrict__ Wmu,
                                             const float* __restrict__ bmu,
                                             const float* __restrict__ Wls,
                                             const float* __restrict__ bls,
                                             float* __restrict__ mu_out,
                                             float* __restrict__ ls_out) {
    __shared__ float h2s[64 * 21];         // 5,376 B
    int t = threadIdx.x;
    int n0 = blockIdx.x * 64;
    if (t < 320) {
        int nl = t / 5, q = t % 5;
        int node = n0 + nl;
        bool live = (node < N_NODES);
        unsigned lo = 0, hi = 0;
        if (live) { lo = row_ptr[node]; hi = row_ptr[node + 1]; }
        float4 a0 = make_float4(0.f, 0.f, 0.f, 0.f);
        float4 a1 = make_float4(0.f, 0.f, 0.f, 0.f);
        float4 a2 = make_float4(0.f, 0.f, 0.f, 0.f);
        float4 a3 = make_float4(0.f, 0.f, 0.f, 0.f);
        const uint2* sp = (const uint2*)src;
        unsigned e = lo;
        for (; e + 4 <= hi; e += 4) {
            unsigned s0 = grec[e], s1 = grec[e + 1], s2 = grec[e + 2], s3 = grec[e + 3];
            uint2 u0 = sp[s0 * 5 + q];
            uint2 u1 = sp[s1 * 5 + q];
            uint2 u2 = sp[s2 * 5 + q];
            uint2 u3 = sp[s3 * 5 + q];
            a0.x += bflo(u0.x); a0.y += bfhi(u0.x); a0.z += bflo(u0.y); a0.w += bfhi(u0.y);
            a1.x += bflo(u1.x); a1.y += bfhi(u1.x); a1.z += bflo(u1.y); a1.w += bfhi(u1.y);
            a2.x += bflo(u2.x); a2.y += bfhi(u2.x); a2.z += bflo(u2.y); a2.w += bfhi(u2.y);
            a3.x += bflo(u3.x); a3.y += bfhi(u3.x); a3.z += bflo(u3.y); a3.w += bfhi(u3.y);
        }
        for (; e < hi; ++e) {
            unsigned s0 = grec[e];
            uint2 u0 = sp[s0 * 5 + q];
            a0.x += bflo(u0.x); a0.y += bfhi(u0.x); a0.z += bflo(u0.y); a0.w += bfhi(u0.y);
        }
        a0.x += a1.x + a2.x + a3.x;
        a0.y += a1.y + a2.y + a3.y;
        a0.z += a1.z + a2.z + a3.z;
        a0.w += a1.w + a2.w + a3.w;
        if (live) {
            float sc = rsqrtf(fmaxf((float)(hi - lo), 1.0f));
            float* row = &h2s[nl * 21 + q * 4];
            row[0] = a0.x * sc; row[1] = a0.y * sc;
            row[2] = a0.z * sc; row[3] = a0.w * sc;
        }
    }
    __syncthreads();
    int wave = t >> 6, lane = t & 63;
    int og = __builtin_amdgcn_readfirstlane(wave);
    int half = og >> 2;
    int co = (og & 3) << 3;
    int node = n0 + lane;
    if (node >= N_NODES) return;
    const float* W  = half ? Wls : Wmu;
    const float* bb = half ? bls : bmu;
    float* out      = half ? ls_out : mu_out;

    uint4 p = *(const uint4*)(pml + (size_t)node * 64 + half * 32 + co);
    float acc[8];
    acc[0] = bf2f((unsigned short)(p.x & 0xFFFFu));
    acc[1] = bf2f((unsigned short)(p.x >> 16));
    acc[2] = bf2f((unsigned short)(p.y & 0xFFFFu));
    acc[3] = bf2f((unsigned short)(p.y >> 16));
    acc[4] = bf2f((unsigned short)(p.z & 0xFFFFu));
    acc[5] = bf2f((unsigned short)(p.z >> 16));
    acc[6] = bf2f((unsigned short)(p.w & 0xFFFFu));
    acc[7] = bf2f((unsigned short)(p.w >> 16));
#pragma unroll
    for (int j = 0; j < 8; ++j) acc[j] += bb[co + j];

#pragma unroll
    for (int i = 0; i < GC_HID; ++i) {
        float x = h2s[lane * 21 + i];
        const float* wr = W + i * Z_DIM + co;
#pragma unroll
        for (int j = 0; j < 8; ++j) acc[j] = fmaf(x, wr[j], acc[j]);
    }
    float4* op = (float4*)(out + (size_t)node * Z_DIM + co);
    op[0] = make_float4(acc[0], acc[1], acc[2], acc[3]);
    op[1] = make_float4(acc[4], acc[5], acc[6], acc[7]);
}

// FUSED gc1 + encoder-partials (R21 local optimum): 256 thr, 64 nodes/blk.
__global__ __launch_bounds__(256) void k_gc1f(const float* __restrict__ nodes,
                                              const float* __restrict__ Wp,
                                              const float* __restrict__ b1,
                                              const float* __restrict__ rs_s,
                                              unsigned short* __restrict__ h_pre,
                                              unsigned short* __restrict__ pml) {
    __shared__ float tile[2][64 * 33];     // 16,896 B
    float* gb = &tile[0][0];               // aliased after last buf0 use
    int t = threadIdx.x;
    int g = __builtin_amdgcn_readfirstlane(t >> 6);  // 0..3: packed-col group
    int lane = t & 63;
    int n0 = blockIdx.x * 64;
    int node = n0 + lane;

    {
        int idx = t;
#pragma unroll
        for (int r = 0; r < 2; ++r, idx += 256) {
            int rr = idx >> 3, c4 = idx & 7;
            int gn = n0 + rr;
            float4 v = (gn < N_NODES)
                ? ((const float4*)nodes)[(size_t)gn * 64 + c4]
                : make_float4(0.f, 0.f, 0.f, 0.f);
            float* dst = &tile[0][rr * 33 + c4 * 4];
            dst[0] = v.x; dst[1] = v.y; dst[2] = v.z; dst[3] = v.w;
        }
    }
    __syncthreads();

    float acc[24];
#pragma unroll
    for (int j = 0; j < 24; ++j) acc[j] = 0.0f;

    for (int c = 0; c < 8; ++c) {
        float4 p0, p1;
        if (c < 7) {
            int idx = t, rr = idx >> 3, c4 = idx & 7, gn = n0 + rr;
            p0 = (gn < N_NODES)
                ? ((const float4*)nodes)[(size_t)gn * 64 + (c + 1) * 8 + c4]
                : make_float4(0.f, 0.f, 0.f, 0.f);
            idx = t + 256; rr = idx >> 3; c4 = idx & 7; gn = n0 + rr;
            p1 = (gn < N_NODES)
                ? ((const float4*)nodes)[(size_t)gn * 64 + (c + 1) * 8 + c4]
                : make_float4(0.f, 0.f, 0.f, 0.f);
        }
        const float* trow  = &tile[c & 1][lane * 33];
        const float* wbase = Wp + (size_t)(c * 32) * 96 + g * 24;
#pragma unroll 4
        for (int kk = 0; kk < 32; ++kk) {
            float x = trow[kk];
            const float* wr = wbase + kk * 96;
#pragma unroll
            for (int j = 0; j < 24; ++j) acc[j] = fmaf(x, wr[j], acc[j]);
        }
        if (c < 7) {
            int idx = t, rr = idx >> 3, c4 = idx & 7;
            float* dst = &tile[(c + 1) & 1][rr * 33 + c4 * 4];
            dst[0] = p0.x; dst[1] = p0.y; dst[2] = p0.z; dst[3] = p0.w;
            idx = t + 256; rr = idx >> 3; c4 = idx & 7;
            dst = &tile[(c + 1) & 1][rr * 33 + c4 * 4];
            dst[0] = p1.x; dst[1] = p1.y; dst[2] = p1.z; dst[3] = p1.w;
        }
        __syncthreads();
    }

    if (node < N_NODES) {
        if (g == 0) {
#pragma unroll
            for (int j = 0; j < GC_HID; ++j) gb[lane * 21 + j] = acc[j] + b1[j];
        } else {
            int base = (g - 1) * 24;
            unsigned short* pp = pml + (size_t)node * 64 + base;
            uint4 q0, q1, q2;
            q0.x = (unsigned)f2bf(acc[0]) | ((unsigned)f2bf(acc[1]) << 16);
            q0.y = (unsigned)f2bf(acc[2]) | ((unsigned)f2bf(acc[3]) << 16);
            q0.z = (unsigned)f2bf(acc[4]) | ((unsigned)f2bf(acc[5]) << 16);
            q0.w = (unsigned)f2bf(acc[6]) | ((unsigned)f2bf(acc[7]) << 16);
            q1.x = (unsigned)f2bf(acc[8]) | ((unsigned)f2bf(acc[9]) << 16);
            q1.y = (unsigned)f2bf(acc[10]) | ((unsigned)f2bf(acc[11]) << 16);
            q1.z = (unsigned)f2bf(acc[12]) | ((unsigned)f2bf(acc[13]) << 16);
            q1.w = (unsigned)f2bf(acc[14]) | ((unsigned)f2bf(acc[15]) << 16);
            q2.x = (unsigned)f2bf(acc[16]) | ((unsigned)f2bf(acc[17]) << 16);
            q2.y = (unsigned)f2bf(acc[18]) | ((unsigned)f2bf(acc[19]) << 16);
            q2.z = (unsigned)f2bf(acc[20]) | ((unsigned)f2bf(acc[21]) << 16);
            q2.w = (unsigned)f2bf(acc[22]) | ((unsigned)f2bf(acc[23]) << 16);
            ((uint4*)pp)[0] = q0;
            ((uint4*)pp)[1] = q1;
            if (g != 3) ((uint4*)pp)[2] = q2;
        }
    }
    __syncthreads();
    if (t < 64) {
        int nn = n0 + t;
        if (nn < N_NODES) {
            float v[GC_HID];
            float mx = -1e30f;
#pragma unroll
            for (int j = 0; j < GC_HID; ++j) {
                v[j] = fmaxf(gb[t * 21 + j], 0.0f);
                mx = fmaxf(mx, v[j]);
            }
            float s = 0.0f;
#pragma unroll
            for (int j = 0; j < GC_HID; ++j) {
                v[j] = __expf(v[j] - mx);
                s += v[j];
            }
            float inv = rs_s[nn] / s;
            unsigned pk[10];
#pragma unroll
            for (int i = 0; i < 10; ++i) {
                float v0 = v[2*i] * inv, v1 = v[2*i+1] * inv;
                pk[i] = (unsigned)f2bf(v0) | ((unsigned)f2bf(v1) << 16);
            }
            uint2* op = (uint2*)(h_pre + (size_t)nn * GC_HID);
#pragma unroll
            for (int i = 0; i < 5; ++i)
                op[i] = make_uint2(pk[2*i], pk[2*i+1]);
        }
    }
}

// FUSED decoder (decd + decx): 512 thr, 128 nodes/block, 782 blocks.
__global__ __launch_bounds__(512) void k_dec(const float* __restrict__ mu,
                                             const float* __restrict__ ls,
                                             const float* __restrict__ eps,
                                             const float* __restrict__ Wd1,
                                             const float* __restrict__ bd1,
                                             const float* __restrict__ Wd2,
                                             const float* __restrict__ bd2,
                                             float* __restrict__ X) {
    __shared__ float ds[128 * 41];         // 20,992 B
    int t = threadIdx.x;
    int wave = t >> 6, lane = t & 63;
    int n0 = blockIdx.x * 128;
    {
        int wu = __builtin_amdgcn_readfirstlane(wave);
        int qd = wu & 3;
        int nh = wu >> 2;
        int nrow = nh * 64 + lane;
        int node = n0 + nrow;
        if (node < N_NODES) {
            float z[Z_DIM];
            const float4* mp = (const float4*)(mu + (size_t)node * Z_DIM);
            const float4* lp = (const float4*)(ls + (size_t)node * Z_DIM);
            const float4* ep = (const float4*)(eps + (size_t)node * Z_DIM);
#pragma unroll
            for (int v = 0; v < Z_DIM / 4; ++v) {
                float4 m = mp[v], l = lp[v], e = ep[v];
                z[4*v+0] = m.x + (1e-4f + __expf(0.5f * l.x)) * e.x;
                z[4*v+1] = m.y + (1e-4f + __expf(0.5f * l.y)) * e.y;
                z[4*v+2] = m.z + (1e-4f + __expf(0.5f * l.z)) * e.z;
                z[4*v+3] = m.w + (1e-4f + __expf(0.5f * l.w)) * e.w;
            }
            float d[10];
#pragma unroll
            for (int j = 0; j < 10; ++j) d[j] = bd1[qd * 10 + j];
#pragma unroll
            for (int i = 0; i < Z_DIM; ++i) {
                float x = z[i];
                const float* wr = Wd1 + i * DEC_HID + qd * 10;
#pragma unroll
                for (int j = 0; j < 10; ++j) d[j] = fmaf(x, wr[j], d[j]);
            }
            float* dst = &ds[nrow * 41 + qd * 10];
#pragma unroll
            for (int j = 0; j < 10; ++j) dst[j] = fmaxf(d[j], 0.0f);
        }
    }
    __syncthreads();
#pragma unroll
    for (int p = 0; p < 2; ++p) {
        int ch = __builtin_amdgcn_readfirstlane(wave >> 1) + p * 4;
        int nrow = (wave & 1) * 64 + lane;
        int node = n0 + nrow;
        if (node < N_NODES) {
            int co = ch << 5;
            float o[32];
#pragma unroll
            for (int j = 0; j < 32; ++j) o[j] = bd2[co + j];
            const float* drow = &ds[nrow * 41];
#pragma unroll 8
            for (int k = 0; k < DEC_HID; ++k) {
                float x = drow[k];
                const float* wr = Wd2 + k * D_FEAT + co;
#pragma unroll
                for (int j = 0; j < 32; ++j) o[j] = fmaf(x, wr[j], o[j]);
            }
            float4* xp = (float4*)(X + (size_t)node * D_FEAT + co);
#pragma unroll
            for (int v = 0; v < 8; ++v)
                xp[v] = make_float4(o[4*v], o[4*v+1], o[4*v+2], o[4*v+3]);
        }
    }
}

extern "C" void kernel_launch(void* const* d_in, const int* in_sizes, int n_in,
                              void* d_out, int out_size, void* d_ws, size_t ws_size,
                              hipStream_t stream) {
    const float* nodes = (const float*)d_in[0];
    const int*   snd   = (const int*)d_in[1];
    const int*   rcv   = (const int*)d_in[2];
    const float* eps   = (const float*)d_in[3];
    const float* W1    = (const float*)d_in[4];
    const float* b1    = (const float*)d_in[5];
    const float* W2    = (const float*)d_in[6];
    const float* b2    = (const float*)d_in[7];
    const float* Wmu   = (const float*)d_in[8];
    const float* bmu   = (const float*)d_in[9];
    const float* Wls   = (const float*)d_in[10];
    const float* bls   = (const float*)d_in[11];
    const float* Wd1   = (const float*)d_in[12];
    const float* bd1   = (const float*)d_in[13];
    const float* Wd2   = (const float*)d_in[14];
    const float* bd2   = (const float*)d_in[15];

    char* ws = (char*)d_ws;
    unsigned short* h_pre    = (unsigned short*)(ws);              // bf16 [N][20]
    unsigned short* agg      = (unsigned short*)(ws + 8000000);    // bf16 [N][20]
    unsigned*       grec     = (unsigned*)(ws + 16000000);
    unsigned short* pml      = (unsigned short*)(ws + 28804096);   // bf16 [N][64]
    unsigned short* cnt_r    = (unsigned short*)(ws + 41608192);
    unsigned*       pref_t   = (unsigned*)(ws + 42836720);
    unsigned*       row_ptr  = (unsigned*)(ws + 45287504);
    unsigned*       gtot     = (unsigned*)(ws + 45687508);
    unsigned*       gbase    = (unsigned*)(ws + 45689076);
    float*          rs_s     = (float*)(ws + 45690648);
    unsigned char*  rec_s    = (unsigned char*)(ws + 46090648);
    unsigned short* srow_s   = (unsigned short*)(ws + 49291672);
    float*          Wpack    = (float*)(ws + 50520192);

    float* X      = (float*)d_out;
    float* mu_out = X + (size_t)N_NODES * D_FEAT;
    float* ls_out = mu_out + (size_t)N_NODES * Z_DIM;

    k_wpack<<<256, 96, 0, stream>>>(W1, Wmu, Wls, Wpack);
    k_hist<<<NBLK, 512, 0, stream>>>(snd, rcv, rec_s, cnt_r, srow_s);
    k_degs<<<SB, 512, 0, stream>>>(rec_s, srow_s, rs_s);
    k_scanB<<<SB, 256, 0, stream>>>(cnt_r, pref_t, gtot);
    k_scanG<<<1, 512, 0, stream>>>(gtot, gbase);
    k_scat2<<<NBLK, 256, 0, stream>>>(snd, rcv, pref_t, gbase, grec);
    k_sort2<<<SB, 256, 0, stream>>>(grec, gbase, row_ptr);

    k_gc1f<<<1563, 256, 0, stream>>>(nodes, Wpack, b1, rs_s, h_pre, pml);
    k_gg1<<<1563, 320, 0, stream>>>(row_ptr, grec, (const unsigned*)h_pre,
                                    W2, b2, rs_s, agg);
    k_gg2<<<1563, 512, 0, stream>>>(row_ptr, grec, (const unsigned*)agg, pml,
                                    Wmu, bmu, Wls, bls, mu_out, ls_out);
    k_dec<<<782, 512, 0, stream>>>(mu_out, ls_out, eps, Wd1, bd1, Wd2, bd2, X);
}

// Round 28
// 350.510 us; speedup vs baseline: 1.0382x; 1.0382x over previous
//
#include <hip/hip_runtime.h>
#include <math.h>

#define N_NODES 100000
#define N_EDGES 3200000
#define D_FEAT 256
#define GC_HID 20
#define DEC_HID 40
#define Z_DIM 32

#define EPB 2048          // edges per sort block
#define NBLK 1563         // ceil(3.2M / 2048)
#define SB 392            // node buckets of 256 (392*256 = 100352)
#define SBSH 8
#define S2CAP 12288       // per-bucket record cap

// ---------------- ws layout (bytes) ----------------
// h_pre (bf16 [N][20]) @ 0          4,000,000
// agg   (bf16 [N][20]) @ 8,000,000  4,000,000
// grec   @16,000,000  12,804,096
// rec_r  @28,804,096  12,804,096   (pml bf16 [N][64] overlays post-gscat)
// srow_r @41,608,192   1,228,518
// pref_t @42,836,720   2,450,784
// row_ptr@45,287,504     400,004
// gtot   @45,687,508       1,568
// gbase  @45,689,076       1,572
// rs_s   @45,690,648     400,000
// rec_s  @46,090,648   3,201,024
// srow_s @49,291,672   1,228,518
// Wpack  @50,520,192      98,304   end = 50,618,496

__device__ inline unsigned short f2bf(float f) {
    unsigned u = __float_as_uint(f);
    return (unsigned short)((u + 0x7FFFu + ((u >> 16) & 1u)) >> 16);
}
__device__ inline float bf2f(unsigned short h) {
    return __uint_as_float((unsigned)h << 16);
}
__device__ inline float bflo(unsigned w) { return __uint_as_float(w << 16); }
__device__ inline float bfhi(unsigned w) { return __uint_as_float(w & 0xFFFF0000u); }

// pack node-row weights: Wpack[k][0:20]=W1[k], [24:56]=Wmu[20+k], [56:88]=Wls[20+k]
__global__ __launch_bounds__(96) void k_wpack(const float* __restrict__ W1,
                                              const float* __restrict__ Wmu,
                                              const float* __restrict__ Wls,
                                              float* __restrict__ Wp) {
    int k = blockIdx.x, j = threadIdx.x;
    float v = 0.0f;
    if (j < 20) v = W1[k * GC_HID + j];
    else if (j >= 24 && j < 56) v = Wmu[(GC_HID + k) * Z_DIM + (j - 24)];
    else if (j >= 56 && j < 88) v = Wls[(GC_HID + k) * Z_DIM + (j - 56)];
    Wp[k * 96 + j] = v;
}

// dual block-local counting sort (receiver u32 + sender u8 streams).
// ZERO global atomics (R13: each device-scope atomic = memory-side write).
// R27 lesson: direct scatter to grec re-introduces cross-block line
// sharing; the coalesced rec_r round-trip + LDS-staged gscat is faster.
__global__ __launch_bounds__(512) void k_sort(const int* __restrict__ snd,
                                              const int* __restrict__ rcv,
                                              unsigned* __restrict__ rec_r,
                                              unsigned char* __restrict__ rec_s,
                                              unsigned short* __restrict__ srow_r,
                                              unsigned short* __restrict__ srow_s) {
    __shared__ int es[EPB], er[EPB];
    __shared__ unsigned scan[SB + 1];
    __shared__ unsigned cur[SB];
    __shared__ unsigned sorted[EPB];
    __shared__ unsigned char sorteds[EPB];
    int b = blockIdx.x, t = threadIdx.x;
    int base = b * EPB;
    int cnt = min(EPB, N_EDGES - base);
    for (int i = t; i < cnt; i += 512) { es[i] = snd[base + i]; er[i] = rcv[base + i]; }

    for (int i = t; i < SB + 1; i += 512) scan[i] = 0u;
    __syncthreads();
    for (int i = t; i < cnt; i += 512) atomicAdd(&scan[(er[i] >> SBSH) + 1], 1u);
    __syncthreads();
    for (int off = 1; off < SB + 1; off <<= 1) {
        unsigned v = (t >= off && t < SB + 1) ? scan[t - off] : 0u;
        __syncthreads();
        if (t < SB + 1) scan[t] += v;
        __syncthreads();
    }
    for (int i = t; i < SB + 1; i += 512) srow_r[(size_t)b * (SB + 1) + i] = (unsigned short)scan[i];
    if (t < SB) cur[t] = scan[t];
    __syncthreads();
    for (int i = t; i < cnt; i += 512) {
        int r = er[i];
        unsigned pos = atomicAdd(&cur[r >> SBSH], 1u);
        sorted[pos] = ((unsigned)(r & 255) << 17) | (unsigned)es[i];
    }
    __syncthreads();
    for (int i = t; i < cnt; i += 512) rec_r[(size_t)base + i] = sorted[i];
    __syncthreads();

    for (int i = t; i < SB + 1; i += 512) scan[i] = 0u;
    __syncthreads();
    for (int i = t; i < cnt; i += 512) atomicAdd(&scan[(es[i] >> SBSH) + 1], 1u);
    __syncthreads();
    for (int off = 1; off < SB + 1; off <<= 1) {
        unsigned v = (t >= off && t < SB + 1) ? scan[t - off] : 0u;
        __syncthreads();
        if (t < SB + 1) scan[t] += v;
        __syncthreads();
    }
    for (int i = t; i < SB + 1; i += 512) srow_s[(size_t)b * (SB + 1) + i] = (unsigned short)scan[i];
    if (t < SB) cur[t] = scan[t];
    __syncthreads();
    for (int i = t; i < cnt; i += 512) {
        int s = es[i];
        unsigned pos = atomicAdd(&cur[s >> SBSH], 1u);
        sorteds[pos] = (unsigned char)(s & 255);
    }
    __syncthreads();
    for (int i = t; i < cnt; i += 512) rec_s[(size_t)base + i] = sorteds[i];
}

// sender-degree via per-bucket LDS histogram over sender-sorted runs
__global__ __launch_bounds__(512) void k_degs(const unsigned char* __restrict__ rec_s,
                                              const unsigned short* __restrict__ srow_s,
                                              float* __restrict__ rs_s) {
    __shared__ unsigned h[256];
    int s = blockIdx.x, t = threadIdx.x;
    if (t < 256) h[t] = 0u;
    __syncthreads();
    for (int k = t; k < NBLK; k += 512) {
        const unsigned short* row = srow_s + (size_t)k * (SB + 1);
        unsigned st = row[s], en = row[s + 1];
        const unsigned char* rp = rec_s + (size_t)k * EPB;
        for (unsigned i = st; i < en; ++i) atomicAdd(&h[rp[i]], 1u);
    }
    __syncthreads();
    if (t < 256) {
        int n = (s << SBSH) + t;
        if (n < N_NODES) rs_s[n] = rsqrtf(fmaxf((float)h[t], 1.0f));
    }
}

// per-bucket prefix over block segments: pref_t[s][k], totals gtot[s]
__global__ __launch_bounds__(256) void k_scanB(const unsigned short* __restrict__ srow_r,
                                               unsigned* __restrict__ pref_t,
                                               unsigned* __restrict__ gtot) {
    __shared__ unsigned buf[256];
    int s = blockIdx.x, t = threadIdx.x;
    unsigned run = 0;
    for (int k0 = 0; k0 < NBLK; k0 += 256) {
        int k = k0 + t;
        unsigned v = 0;
        if (k < NBLK) {
            const unsigned short* row = srow_r + (size_t)k * (SB + 1);
            v = (unsigned)row[s + 1] - (unsigned)row[s];
        }
        buf[t] = v;
        __syncthreads();
        for (int off = 1; off < 256; off <<= 1) {
            unsigned x = (t >= off) ? buf[t - off] : 0u;
            __syncthreads();
            buf[t] += x;
            __syncthreads();
        }
        if (k < NBLK) pref_t[(size_t)s * NBLK + k] = run + (buf[t] - v);
        unsigned tot = buf[255];
        __syncthreads();
        run += tot;
    }
    if (t == 0) gtot[s] = run;
}

// exclusive scan of bucket totals -> gbase[SB+1]
__global__ __launch_bounds__(512) void k_scanG(const unsigned* __restrict__ gtot,
                                               unsigned* __restrict__ gbase) {
    __shared__ unsigned buf[SB];
    int t = threadIdx.x;
    if (t < SB) buf[t] = gtot[t];
    __syncthreads();
    for (int off = 1; off < SB; off <<= 1) {
        unsigned x = (t >= off && t < SB) ? buf[t - off] : 0u;
        __syncthreads();
        if (t < SB) buf[t] += x;
        __syncthreads();
    }
    if (t < SB) gbase[t + 1] = buf[t];
    if (t == 0) gbase[0] = 0u;
}

// scatter block-sorted records to global bucket-sorted order
__global__ __launch_bounds__(256) void k_gscat(const unsigned* __restrict__ rec_r,
                                               const unsigned short* __restrict__ srow_r,
                                               const unsigned* __restrict__ pref_t,
                                               const unsigned* __restrict__ gbase,
                                               unsigned* __restrict__ grec) {
    __shared__ unsigned recs[EPB];
    __shared__ unsigned short srow[SB + 1];
    int b = blockIdx.x, t = threadIdx.x;
    int base = b * EPB;
    int cnt = min(EPB, N_EDGES - base);
    for (int i = t; i < cnt; i += 256) recs[i] = rec_r[(size_t)base + i];
    for (int i = t; i < SB + 1; i += 256) srow[i] = srow_r[(size_t)b * (SB + 1) + i];
    __syncthreads();
    for (int s = t; s < SB; s += 256) {
        unsigned lo = srow[s], hi = srow[s + 1];
        if (lo == hi) continue;
        unsigned dst = gbase[s] + pref_t[(size_t)s * NBLK + b];
        for (unsigned i = lo; i < hi; ++i) grec[dst + (i - lo)] = recs[i];
    }
}

// within-bucket counting sort by local receiver (in-place) + CSR row_ptr
__global__ __launch_bounds__(256) void k_sort2(unsigned* __restrict__ grec,
                                               const unsigned* __restrict__ gbase,
                                               unsigned* __restrict__ row_ptr) {
    __shared__ unsigned recs[S2CAP];     // 48 KB
    __shared__ unsigned hist[256];
    __shared__ unsigned scan[256];
    __shared__ unsigned cur[256];
    int s = blockIdx.x, t = threadIdx.x;
    unsigned lo = gbase[s], hi = gbase[s + 1];
    unsigned cnt = min(hi - lo, (unsigned)S2CAP);
    for (unsigned i = t; i < cnt; i += 256) recs[i] = grec[lo + i];
    hist[t] = 0u;
    __syncthreads();
    for (unsigned i = t; i < cnt; i += 256) atomicAdd(&hist[recs[i] >> 17], 1u);
    __syncthreads();
    unsigned v = hist[t];
    scan[t] = v;
    __syncthreads();
    for (int off = 1; off < 256; off <<= 1) {
        unsigned x = (t >= off) ? scan[t - off] : 0u;
        __syncthreads();
        scan[t] += x;
        __syncthreads();
    }
    unsigned excl = scan[t] - v;
    {
        int n = (s << SBSH) + t;
        if (n <= N_NODES) row_ptr[n] = lo + excl;
    }
    cur[t] = excl;
    __syncthreads();
    for (unsigned i = t; i < cnt; i += 256) {
        unsigned rec = recs[i];
        unsigned pos = atomicAdd(&cur[rec >> 17], 1u);
        grec[lo + pos] = rec & 0x1FFFFu;
    }
}

// FUSED gather1 + gc2: block = 64 nodes x 5 lanes (320 thr).
// src is bf16 [N][20] (40B rows, fits XCD L2); lane q reads uint2 (4 bf16).
__global__ __launch_bounds__(320) void k_gg1(const unsigned* __restrict__ row_ptr,
                                             const unsigned* __restrict__ grec,
                                             const unsigned* __restrict__ src,
                                             const float* __restrict__ W2,
                                             const float* __restrict__ b2,
                                             const float* __restrict__ rs_s,
                                             unsigned short* __restrict__ h2_pre) {
    __shared__ float h1[64 * 21];          // 5,376 B
    __shared__ float Wsh[GC_HID * GC_HID];
    __shared__ float bsh[GC_HID];
    int t = threadIdx.x;
    if (t < GC_HID * GC_HID) Wsh[t] = W2[t];
    if (t >= 400 && t < 400 + GC_HID) bsh[t - 400] = b2[t - 400];
    int nl = t / 5, q = t % 5;
    int node = blockIdx.x * 64 + nl;
    bool live = (node < N_NODES);
    unsigned lo = 0, hi = 0;
    if (live) { lo = row_ptr[node]; hi = row_ptr[node + 1]; }
    float4 a0 = make_float4(0.f, 0.f, 0.f, 0.f);
    float4 a1 = make_float4(0.f, 0.f, 0.f, 0.f);
    float4 a2 = make_float4(0.f, 0.f, 0.f, 0.f);
    float4 a3 = make_float4(0.f, 0.f, 0.f, 0.f);
    const uint2* sp = (const uint2*)src;
    unsigned e = lo;
    for (; e + 4 <= hi; e += 4) {
        unsigned s0 = grec[e], s1 = grec[e + 1], s2 = grec[e + 2], s3 = grec[e + 3];
        uint2 u0 = sp[s0 * 5 + q];
        uint2 u1 = sp[s1 * 5 + q];
        uint2 u2 = sp[s2 * 5 + q];
        uint2 u3 = sp[s3 * 5 + q];
        a0.x += bflo(u0.x); a0.y += bfhi(u0.x); a0.z += bflo(u0.y); a0.w += bfhi(u0.y);
        a1.x += bflo(u1.x); a1.y += bfhi(u1.x); a1.z += bflo(u1.y); a1.w += bfhi(u1.y);
        a2.x += bflo(u2.x); a2.y += bfhi(u2.x); a2.z += bflo(u2.y); a2.w += bfhi(u2.y);
        a3.x += bflo(u3.x); a3.y += bfhi(u3.x); a3.z += bflo(u3.y); a3.w += bfhi(u3.y);
    }
    for (; e < hi; ++e) {
        unsigned s0 = grec[e];
        uint2 u0 = sp[s0 * 5 + q];
        a0.x += bflo(u0.x); a0.y += bfhi(u0.x); a0.z += bflo(u0.y); a0.w += bfhi(u0.y);
    }
    a0.x += a1.x + a2.x + a3.x;
    a0.y += a1.y + a2.y + a3.y;
    a0.z += a1.z + a2.z + a3.z;
    a0.w += a1.w + a2.w + a3.w;
    if (live) {
        float sc = rsqrtf(fmaxf((float)(hi - lo), 1.0f));
        float* row = &h1[nl * 21 + q * 4];
        row[0] = a0.x * sc; row[1] = a0.y * sc;
        row[2] = a0.z * sc; row[3] = a0.w * sc;
    }
    __syncthreads();
    if (t < 64) {
        int nn = blockIdx.x * 64 + t;
        if (nn < N_NODES) {
            float hv[GC_HID];
#pragma unroll
            for (int i = 0; i < GC_HID; ++i) hv[i] = h1[t * 21 + i];
            float o[GC_HID];
#pragma unroll
            for (int j = 0; j < GC_HID; ++j) o[j] = bsh[j];
#pragma unroll
            for (int i = 0; i < GC_HID; ++i) {
                float x = hv[i];
#pragma unroll
                for (int j = 0; j < GC_HID; ++j) o[j] = fmaf(x, Wsh[i * GC_HID + j], o[j]);
            }
            float mx = -1e30f;
#pragma unroll
            for (int j = 0; j < GC_HID; ++j) { o[j] = fmaxf(o[j], 0.0f); mx = fmaxf(mx, o[j]); }
            float s = 0.0f;
#pragma unroll
            for (int j = 0; j < GC_HID; ++j) { o[j] = __expf(o[j] - mx); s += o[j]; }
            float inv = rs_s[nn] / s;
            unsigned pk[10];
#pragma unroll
            for (int i = 0; i < 10; ++i) {
                float v0 = o[2*i] * inv, v1 = o[2*i+1] * inv;
                pk[i] = (unsigned)f2bf(v0) | ((unsigned)f2bf(v1) << 16);
            }
            uint2* op = (uint2*)(h2_pre + (size_t)nn * GC_HID);
#pragma unroll
            for (int i = 0; i < 5; ++i)
                op[i] = make_uint2(pk[2*i], pk[2*i+1]);
        }
    }
}

// FUSED gather2 + encoder finish: 512 thr, 64 nodes.
__global__ __launch_bounds__(512) void k_gg2(const unsigned* __restrict__ row_ptr,
                                             const unsigned* __restrict__ grec,
                                             const unsigned* __restrict__ src,
                                             const unsigned short* __restrict__ pml,
                                             const float* __restrict__ Wmu,
                                             const float* __restrict__ bmu,
                                             const float* __restrict__ Wls,
                                             const float* __restrict__ bls,
                                             float* __restrict__ mu_out,
                                             float* __restrict__ ls_out) {
    __shared__ float h2s[64 * 21];         // 5,376 B
    int t = threadIdx.x;
    int n0 = blockIdx.x * 64;
    if (t < 320) {
        int nl = t / 5, q = t % 5;
        int node = n0 + nl;
        bool live = (node < N_NODES);
        unsigned lo = 0, hi = 0;
        if (live) { lo = row_ptr[node]; hi = row_ptr[node + 1]; }
        float4 a0 = make_float4(0.f, 0.f, 0.f, 0.f);
        float4 a1 = make_float4(0.f, 0.f, 0.f, 0.f);
        float4 a2 = make_float4(0.f, 0.f, 0.f, 0.f);
        float4 a3 = make_float4(0.f, 0.f, 0.f, 0.f);
        const uint2* sp = (const uint2*)src;
        unsigned e = lo;
        for (; e + 4 <= hi; e += 4) {
            unsigned s0 = grec[e], s1 = grec[e + 1], s2 = grec[e + 2], s3 = grec[e + 3];
            uint2 u0 = sp[s0 * 5 + q];
            uint2 u1 = sp[s1 * 5 + q];
            uint2 u2 = sp[s2 * 5 + q];
            uint2 u3 = sp[s3 * 5 + q];
            a0.x += bflo(u0.x); a0.y += bfhi(u0.x); a0.z += bflo(u0.y); a0.w += bfhi(u0.y);
            a1.x += bflo(u1.x); a1.y += bfhi(u1.x); a1.z += bflo(u1.y); a1.w += bfhi(u1.y);
            a2.x += bflo(u2.x); a2.y += bfhi(u2.x); a2.z += bflo(u2.y); a2.w += bfhi(u2.y);
            a3.x += bflo(u3.x); a3.y += bfhi(u3.x); a3.z += bflo(u3.y); a3.w += bfhi(u3.y);
        }
        for (; e < hi; ++e) {
            unsigned s0 = grec[e];
            uint2 u0 = sp[s0 * 5 + q];
            a0.x += bflo(u0.x); a0.y += bfhi(u0.x); a0.z += bflo(u0.y); a0.w += bfhi(u0.y);
        }
        a0.x += a1.x + a2.x + a3.x;
        a0.y += a1.y + a2.y + a3.y;
        a0.z += a1.z + a2.z + a3.z;
        a0.w += a1.w + a2.w + a3.w;
        if (live) {
            float sc = rsqrtf(fmaxf((float)(hi - lo), 1.0f));
            float* row = &h2s[nl * 21 + q * 4];
            row[0] = a0.x * sc; row[1] = a0.y * sc;
            row[2] = a0.z * sc; row[3] = a0.w * sc;
        }
    }
    __syncthreads();
    int wave = t >> 6, lane = t & 63;
    int og = __builtin_amdgcn_readfirstlane(wave);
    int half = og >> 2;
    int co = (og & 3) << 3;
    int node = n0 + lane;
    if (node >= N_NODES) return;
    const float* W  = half ? Wls : Wmu;
    const float* bb = half ? bls : bmu;
    float* out      = half ? ls_out : mu_out;

    uint4 p = *(const uint4*)(pml + (size_t)node * 64 + half * 32 + co);
    float acc[8];
    acc[0] = bf2f((unsigned short)(p.x & 0xFFFFu));
    acc[1] = bf2f((unsigned short)(p.x >> 16));
    acc[2] = bf2f((unsigned short)(p.y & 0xFFFFu));
    acc[3] = bf2f((unsigned short)(p.y >> 16));
    acc[4] = bf2f((unsigned short)(p.z & 0xFFFFu));
    acc[5] = bf2f((unsigned short)(p.z >> 16));
    acc[6] = bf2f((unsigned short)(p.w & 0xFFFFu));
    acc[7] = bf2f((unsigned short)(p.w >> 16));
#pragma unroll
    for (int j = 0; j < 8; ++j) acc[j] += bb[co + j];

#pragma unroll
    for (int i = 0; i < GC_HID; ++i) {
        float x = h2s[lane * 21 + i];
        const float* wr = W + i * Z_DIM + co;
#pragma unroll
        for (int j = 0; j < 8; ++j) acc[j] = fmaf(x, wr[j], acc[j]);
    }
    float4* op = (float4*)(out + (size_t)node * Z_DIM + co);
    op[0] = make_float4(acc[0], acc[1], acc[2], acc[3]);
    op[1] = make_float4(acc[4], acc[5], acc[6], acc[7]);
}

// FUSED gc1 + encoder-partials (R21 local optimum): 256 thr, 64 nodes/blk.
__global__ __launch_bounds__(256) void k_gc1f(const float* __restrict__ nodes,
                                              const float* __restrict__ Wp,
                                              const float* __restrict__ b1,
                                              const float* __restrict__ rs_s,
                                              unsigned short* __restrict__ h_pre,
                                              unsigned short* __restrict__ pml) {
    __shared__ float tile[2][64 * 33];     // 16,896 B
    float* gb = &tile[0][0];               // aliased after last buf0 use
    int t = threadIdx.x;
    int g = __builtin_amdgcn_readfirstlane(t >> 6);  // 0..3: packed-col group
    int lane = t & 63;
    int n0 = blockIdx.x * 64;
    int node = n0 + lane;

    {
        int idx = t;
#pragma unroll
        for (int r = 0; r < 2; ++r, idx += 256) {
            int rr = idx >> 3, c4 = idx & 7;
            int gn = n0 + rr;
            float4 v = (gn < N_NODES)
                ? ((const float4*)nodes)[(size_t)gn * 64 + c4]
                : make_float4(0.f, 0.f, 0.f, 0.f);
            float* dst = &tile[0][rr * 33 + c4 * 4];
            dst[0] = v.x; dst[1] = v.y; dst[2] = v.z; dst[3] = v.w;
        }
    }
    __syncthreads();

    float acc[24];
#pragma unroll
    for (int j = 0; j < 24; ++j) acc[j] = 0.0f;

    for (int c = 0; c < 8; ++c) {
        float4 p0, p1;
        if (c < 7) {
            int idx = t, rr = idx >> 3, c4 = idx & 7, gn = n0 + rr;
            p0 = (gn < N_NODES)
                ? ((const float4*)nodes)[(size_t)gn * 64 + (c + 1) * 8 + c4]
                : make_float4(0.f, 0.f, 0.f, 0.f);
            idx = t + 256; rr = idx >> 3; c4 = idx & 7; gn = n0 + rr;
            p1 = (gn < N_NODES)
                ? ((const float4*)nodes)[(size_t)gn * 64 + (c + 1) * 8 + c4]
                : make_float4(0.f, 0.f, 0.f, 0.f);
        }
        const float* trow  = &tile[c & 1][lane * 33];
        const float* wbase = Wp + (size_t)(c * 32) * 96 + g * 24;
#pragma unroll 4
        for (int kk = 0; kk < 32; ++kk) {
            float x = trow[kk];
            const float* wr = wbase + kk * 96;
#pragma unroll
            for (int j = 0; j < 24; ++j) acc[j] = fmaf(x, wr[j], acc[j]);
        }
        if (c < 7) {
            int idx = t, rr = idx >> 3, c4 = idx & 7;
            float* dst = &tile[(c + 1) & 1][rr * 33 + c4 * 4];
            dst[0] = p0.x; dst[1] = p0.y; dst[2] = p0.z; dst[3] = p0.w;
            idx = t + 256; rr = idx >> 3; c4 = idx & 7;
            dst = &tile[(c + 1) & 1][rr * 33 + c4 * 4];
            dst[0] = p1.x; dst[1] = p1.y; dst[2] = p1.z; dst[3] = p1.w;
        }
        __syncthreads();
    }

    if (node < N_NODES) {
        if (g == 0) {
#pragma unroll
            for (int j = 0; j < GC_HID; ++j) gb[lane * 21 + j] = acc[j] + b1[j];
        } else {
            int base = (g - 1) * 24;
            unsigned short* pp = pml + (size_t)node * 64 + base;
            uint4 q0, q1, q2;
            q0.x = (unsigned)f2bf(acc[0]) | ((unsigned)f2bf(acc[1]) << 16);
            q0.y = (unsigned)f2bf(acc[2]) | ((unsigned)f2bf(acc[3]) << 16);
            q0.z = (unsigned)f2bf(acc[4]) | ((unsigned)f2bf(acc[5]) << 16);
            q0.w = (unsigned)f2bf(acc[6]) | ((unsigned)f2bf(acc[7]) << 16);
            q1.x = (unsigned)f2bf(acc[8]) | ((unsigned)f2bf(acc[9]) << 16);
            q1.y = (unsigned)f2bf(acc[10]) | ((unsigned)f2bf(acc[11]) << 16);
            q1.z = (unsigned)f2bf(acc[12]) | ((unsigned)f2bf(acc[13]) << 16);
            q1.w = (unsigned)f2bf(acc[14]) | ((unsigned)f2bf(acc[15]) << 16);
            q2.x = (unsigned)f2bf(acc[16]) | ((unsigned)f2bf(acc[17]) << 16);
            q2.y = (unsigned)f2bf(acc[18]) | ((unsigned)f2bf(acc[19]) << 16);
            q2.z = (unsigned)f2bf(acc[20]) | ((unsigned)f2bf(acc[21]) << 16);
            q2.w = (unsigned)f2bf(acc[22]) | ((unsigned)f2bf(acc[23]) << 16);
            ((uint4*)pp)[0] = q0;
            ((uint4*)pp)[1] = q1;
            if (g != 3) ((uint4*)pp)[2] = q2;
        }
    }
    __syncthreads();
    if (t < 64) {
        int nn = n0 + t;
        if (nn < N_NODES) {
            float v[GC_HID];
            float mx = -1e30f;
#pragma unroll
            for (int j = 0; j < GC_HID; ++j) {
                v[j] = fmaxf(gb[t * 21 + j], 0.0f);
                mx = fmaxf(mx, v[j]);
            }
            float s = 0.0f;
#pragma unroll
            for (int j = 0; j < GC_HID; ++j) {
                v[j] = __expf(v[j] - mx);
                s += v[j];
            }
            float inv = rs_s[nn] / s;
            unsigned pk[10];
#pragma unroll
            for (int i = 0; i < 10; ++i) {
                float v0 = v[2*i] * inv, v1 = v[2*i+1] * inv;
                pk[i] = (unsigned)f2bf(v0) | ((unsigned)f2bf(v1) << 16);
            }
            uint2* op = (uint2*)(h_pre + (size_t)nn * GC_HID);
#pragma unroll
            for (int i = 0; i < 5; ++i)
                op[i] = make_uint2(pk[2*i], pk[2*i+1]);
        }
    }
}

// FUSED decoder (decd + decx): 512 thr, 128 nodes/block, 782 blocks.
__global__ __launch_bounds__(512) void k_dec(const float* __restrict__ mu,
                                             const float* __restrict__ ls,
                                             const float* __restrict__ eps,
                                             const float* __restrict__ Wd1,
                                             const float* __restrict__ bd1,
                                             const float* __restrict__ Wd2,
                                             const float* __restrict__ bd2,
                                             float* __restrict__ X) {
    __shared__ float ds[128 * 41];         // 20,992 B
    int t = threadIdx.x;
    int wave = t >> 6, lane = t & 63;
    int n0 = blockIdx.x * 128;
    {
        int wu = __builtin_amdgcn_readfirstlane(wave);
        int qd = wu & 3;
        int nh = wu >> 2;
        int nrow = nh * 64 + lane;
        int node = n0 + nrow;
        if (node < N_NODES) {
            float z[Z_DIM];
            const float4* mp = (const float4*)(mu + (size_t)node * Z_DIM);
            const float4* lp = (const float4*)(ls + (size_t)node * Z_DIM);
            const float4* ep = (const float4*)(eps + (size_t)node * Z_DIM);
#pragma unroll
            for (int v = 0; v < Z_DIM / 4; ++v) {
                float4 m = mp[v], l = lp[v], e = ep[v];
                z[4*v+0] = m.x + (1e-4f + __expf(0.5f * l.x)) * e.x;
                z[4*v+1] = m.y + (1e-4f + __expf(0.5f * l.y)) * e.y;
                z[4*v+2] = m.z + (1e-4f + __expf(0.5f * l.z)) * e.z;
                z[4*v+3] = m.w + (1e-4f + __expf(0.5f * l.w)) * e.w;
            }
            float d[10];
#pragma unroll
            for (int j = 0; j < 10; ++j) d[j] = bd1[qd * 10 + j];
#pragma unroll
            for (int i = 0; i < Z_DIM; ++i) {
                float x = z[i];
                const float* wr = Wd1 + i * DEC_HID + qd * 10;
#pragma unroll
                for (int j = 0; j < 10; ++j) d[j] = fmaf(x, wr[j], d[j]);
            }
            float* dst = &ds[nrow * 41 + qd * 10];
#pragma unroll
            for (int j = 0; j < 10; ++j) dst[j] = fmaxf(d[j], 0.0f);
        }
    }
    __syncthreads();
#pragma unroll
    for (int p = 0; p < 2; ++p) {
        int ch = __builtin_amdgcn_readfirstlane(wave >> 1) + p * 4;
        int nrow = (wave & 1) * 64 + lane;
        int node = n0 + nrow;
        if (node < N_NODES) {
            int co = ch << 5;
            float o[32];
#pragma unroll
            for (int j = 0; j < 32; ++j) o[j] = bd2[co + j];
            const float* drow = &ds[nrow * 41];
#pragma unroll 8
            for (int k = 0; k < DEC_HID; ++k) {
                float x = drow[k];
                const float* wr = Wd2 + k * D_FEAT + co;
#pragma unroll
                for (int j = 0; j < 32; ++j) o[j] = fmaf(x, wr[j], o[j]);
            }
            float4* xp = (float4*)(X + (size_t)node * D_FEAT + co);
#pragma unroll
            for (int v = 0; v < 8; ++v)
                xp[v] = make_float4(o[4*v], o[4*v+1], o[4*v+2], o[4*v+3]);
        }
    }
}

extern "C" void kernel_launch(void* const* d_in, const int* in_sizes, int n_in,
                              void* d_out, int out_size, void* d_ws, size_t ws_size,
                              hipStream_t stream) {
    const float* nodes = (const float*)d_in[0];
    const int*   snd   = (const int*)d_in[1];
    const int*   rcv   = (const int*)d_in[2];
    const float* eps   = (const float*)d_in[3];
    const float* W1    = (const float*)d_in[4];
    const float* b1    = (const float*)d_in[5];
    const float* W2    = (const float*)d_in[6];
    const float* b2    = (const float*)d_in[7];
    const float* Wmu   = (const float*)d_in[8];
    const float* bmu   = (const float*)d_in[9];
    const float* Wls   = (const float*)d_in[10];
    const float* bls   = (const float*)d_in[11];
    const float* Wd1   = (const float*)d_in[12];
    const float* bd1   = (const float*)d_in[13];
    const float* Wd2   = (const float*)d_in[14];
    const float* bd2   = (const float*)d_in[15];

    char* ws = (char*)d_ws;
    unsigned short* h_pre    = (unsigned short*)(ws);              // bf16 [N][20]
    unsigned short* agg      = (unsigned short*)(ws + 8000000);    // bf16 [N][20]
    unsigned*       grec     = (unsigned*)(ws + 16000000);
    unsigned*       rec_r    = (unsigned*)(ws + 28804096);
    unsigned short* pml      = (unsigned short*)(ws + 28804096);   // overlays rec_r post-gscat
    unsigned short* srow_r   = (unsigned short*)(ws + 41608192);
    unsigned*       pref_t   = (unsigned*)(ws + 42836720);
    unsigned*       row_ptr  = (unsigned*)(ws + 45287504);
    unsigned*       gtot     = (unsigned*)(ws + 45687508);
    unsigned*       gbase    = (unsigned*)(ws + 45689076);
    float*          rs_s     = (float*)(ws + 45690648);
    unsigned char*  rec_s    = (unsigned char*)(ws + 46090648);
    unsigned short* srow_s   = (unsigned short*)(ws + 49291672);
    float*          Wpack    = (float*)(ws + 50520192);

    float* X      = (float*)d_out;
    float* mu_out = X + (size_t)N_NODES * D_FEAT;
    float* ls_out = mu_out + (size_t)N_NODES * Z_DIM;

    k_wpack<<<256, 96, 0, stream>>>(W1, Wmu, Wls, Wpack);
    k_sort<<<NBLK, 512, 0, stream>>>(snd, rcv, rec_r, rec_s, srow_r, srow_s);
    k_degs<<<SB, 512, 0, stream>>>(rec_s, srow_s, rs_s);
    k_scanB<<<SB, 256, 0, stream>>>(srow_r, pref_t, gtot);
    k_scanG<<<1, 512, 0, stream>>>(gtot, gbase);
    k_gscat<<<NBLK, 256, 0, stream>>>(rec_r, srow_r, pref_t, gbase, grec);
    k_sort2<<<SB, 256, 0, stream>>>(grec, gbase, row_ptr);

    k_gc1f<<<1563, 256, 0, stream>>>(nodes, Wpack, b1, rs_s, h_pre, pml);
    k_gg1<<<1563, 320, 0, stream>>>(row_ptr, grec, (const unsigned*)h_pre,
                                    W2, b2, rs_s, agg);
    k_gg2<<<1563, 512, 0, stream>>>(row_ptr, grec, (const unsigned*)agg, pml,
                                    Wmu, bmu, Wls, bls, mu_out, ls_out);
    k_dec<<<782, 512, 0, stream>>>(mu_out, ls_out, eps, Wd1, bd1, Wd2, bd2, X);
}